// Round 4
// baseline (1043.734 us; speedup 1.0000x reference)
//
#include <hip/hip_runtime.h>

// SparseMoE: B=4,S=2048 -> T=8192 tokens, D=1024, FF=4096, E=8, top-2.
// R4: R3 (m97-structure, proven 1030us) + BK 32->64 (half the barrier-drain
// stall events per FLOP) with rule-#21 swizzle: linear LDS dest (gl_lds),
// XOR-pre-swizzled GLOBAL source (16B chunk c ^= row&7), same XOR on ds_read.
// R1 failed BK=64 because un-swizzled 128B rows = 16-way conflicts (5.15e7);
// this keeps R3's conflict profile. gemm2 additionally K-split x2 (atomicAdd
// epilogue makes it free) -> 2048 real blocks, no 3-block tail quantization.

#define T_TOK 8192
#define D_EMB 1024
#define DFF   4096
#define N_EXP 8
#define BM 128
#define BN 128
#define BK 64

typedef __attribute__((ext_vector_type(8))) short bf16x8;
typedef __attribute__((ext_vector_type(4))) float floatx4;
typedef unsigned short bf16_t;

__device__ __forceinline__ bf16_t f2bf(float f) {
  union { float f; unsigned u; } a; a.f = f;
  unsigned u = a.u;
  return (bf16_t)((u + 0x7fffu + ((u >> 16) & 1u)) >> 16);  // RNE
}

// async global->LDS, 16B per lane. LDS dest = wave-uniform base + lane*16;
// global src is per-lane (gather + swizzle OK).
__device__ __forceinline__ void gl_lds16(const bf16_t* g, bf16_t* l) {
  __builtin_amdgcn_global_load_lds(
      (const __attribute__((address_space(1))) void*)g,
      (__attribute__((address_space(3))) void*)l, 16, 0, 0);
}

// ---------------- cvt x -> bf16 ----------------
__global__ __launch_bounds__(256) void cvt_x_k(const float* __restrict__ x,
                                               bf16_t* __restrict__ xb) {
  int i = (blockIdx.x * 256 + threadIdx.x) * 4;
  float4 v = *(const float4*)(x + i);
  ushort4 o;
  o.x = f2bf(v.x); o.y = f2bf(v.y); o.z = f2bf(v.z); o.w = f2bf(v.w);
  *(ushort4*)(xb + i) = o;
}

// ------------- transpose+cvt: in [E][K][N] f32 -> out [E][N][K] bf16 -------------
__global__ __launch_bounds__(256) void tcvt_k(const float* __restrict__ in,
                                              bf16_t* __restrict__ outp,
                                              int K, int N) {
  __shared__ float tile[32][33];
  int e  = blockIdx.z;
  int n0 = blockIdx.x * 32;
  int k0 = blockIdx.y * 32;
  int tx = threadIdx.x;  // 0..31
  int ty = threadIdx.y;  // 0..7
  const float* src = in + (size_t)e * K * N;
#pragma unroll
  for (int l = 0; l < 32; l += 8)
    tile[ty + l][tx] = src[(size_t)(k0 + ty + l) * N + (n0 + tx)];
  __syncthreads();
  bf16_t* dst = outp + (size_t)e * K * N;
#pragma unroll
  for (int l = 0; l < 32; l += 8)
    dst[(size_t)(n0 + ty + l) * K + (k0 + tx)] = f2bf(tile[tx][ty + l]);
}

// ---------------- router ----------------
__global__ __launch_bounds__(256) void router_k(
    const float* __restrict__ x, const float* __restrict__ nu,
    const float* __restrict__ wg, const float* __restrict__ bgp,
    const float* __restrict__ wn, const float* __restrict__ bnp,
    int* __restrict__ cnt, int* __restrict__ tok, float* __restrict__ gate) {
  int t = blockIdx.x;
  int tid = threadIdx.x;
  float gl[8] = {0,0,0,0,0,0,0,0};
  float nl[8] = {0,0,0,0,0,0,0,0};
  const float* xr = x + (size_t)t * D_EMB;
  for (int i = tid; i < D_EMB; i += 256) {
    float xv = xr[i];
    float4 a0 = *(const float4*)(wg + i * 8);
    float4 a1 = *(const float4*)(wg + i * 8 + 4);
    float4 c0 = *(const float4*)(wn + i * 8);
    float4 c1 = *(const float4*)(wn + i * 8 + 4);
    gl[0] += xv * a0.x; gl[1] += xv * a0.y; gl[2] += xv * a0.z; gl[3] += xv * a0.w;
    gl[4] += xv * a1.x; gl[5] += xv * a1.y; gl[6] += xv * a1.z; gl[7] += xv * a1.w;
    nl[0] += xv * c0.x; nl[1] += xv * c0.y; nl[2] += xv * c0.z; nl[3] += xv * c0.w;
    nl[4] += xv * c1.x; nl[5] += xv * c1.y; nl[6] += xv * c1.z; nl[7] += xv * c1.w;
  }
  __shared__ float red[4][16];
  int lane = tid & 63;
  int wv = tid >> 6;
#pragma unroll
  for (int o = 0; o < 16; ++o) {
    float v = (o < 8) ? gl[o] : nl[o - 8];
#pragma unroll
    for (int s = 32; s > 0; s >>= 1) v += __shfl_down(v, s, 64);
    if (lane == 0) red[wv][o] = v;
  }
  __syncthreads();
  if (tid == 0) {
    float noisy[8];
#pragma unroll
    for (int e = 0; e < 8; ++e) {
      float lg = red[0][e] + red[1][e] + red[2][e] + red[3][e] + bgp[e];
      float nz = red[0][8 + e] + red[1][8 + e] + red[2][8 + e] + red[3][8 + e] + bnp[e];
      float sp = fmaxf(nz, 0.f) + log1pf(expf(-fabsf(nz)));  // stable softplus
      noisy[e] = lg + nu[(size_t)t * 8 + e] * sp;
    }
    int e1 = 0;
#pragma unroll
    for (int e = 1; e < 8; ++e) if (noisy[e] > noisy[e1]) e1 = e;
    int e2 = -1;
#pragma unroll
    for (int e = 0; e < 8; ++e) {
      if (e == e1) continue;
      if (e2 < 0 || noisy[e] > noisy[e2]) e2 = e;
    }
    float d = expf(noisy[e2] - noisy[e1]);   // <= 1, no overflow
    float g1 = 1.f / (1.f + d);
    float g2 = d / (1.f + d);
    int p1 = atomicAdd(&cnt[e1], 1);
    tok[e1 * T_TOK + p1] = t; gate[e1 * T_TOK + p1] = g1;
    int p2 = atomicAdd(&cnt[e2], 1);
    tok[e2 * T_TOK + p2] = t; gate[e2 * T_TOK + p2] = g2;
  }
}

// ---------------- scan (8 experts) ----------------
__global__ void scan_k(const int* __restrict__ cnt, int* __restrict__ offs) {
  if (threadIdx.x == 0 && blockIdx.x == 0) {
    int a = 0;
    for (int e = 0; e < N_EXP; ++e) { offs[e] = a; a += cnt[e]; }
    offs[N_EXP] = a;
  }
}

// ---------------- GEMM1: h = relu(x_gathered @ w1 + b1), bf16 out ----------------
// 128x128, BK=64, 4 waves, single-buffer LDS, src-swizzled staging.
__global__ __launch_bounds__(256) void gemm1_k(
    const bf16_t* __restrict__ xb, const bf16_t* __restrict__ w1T,
    const float* __restrict__ b1p, const int* __restrict__ cnt,
    const int* __restrict__ offs, const int* __restrict__ tok,
    bf16_t* __restrict__ h) {
  const int NT = DFF / BN;    // 32
  const int MT = T_TOK / BM;  // 64
  const int NWG = N_EXP * MT * NT;  // 16384, %8==0 -> bijective swizzle
  int b0 = blockIdx.x;
  int bid = (b0 & 7) * (NWG >> 3) + (b0 >> 3);  // chunked per-XCD
  int e = bid / (MT * NT);
  int rem = bid % (MT * NT);
  int mt = rem / NT;
  int nt = rem % NT;
  int cnte = cnt[e];
  if (mt * BM >= cnte) return;
  int rows = min(BM, cnte - mt * BM);

  __shared__ bf16_t As[BM * BK];  // 16 KB, linear (gl_lds dest)
  __shared__ bf16_t Bs[BN * BK];  // 16 KB

  int tid = threadIdx.x;
  int lane = tid & 63;
  int wv = tid >> 6;          // 0..3
  int rq = tid >> 3;          // 0..31 (row within 32-row staging round)
  int c8 = tid & 7;           // 16B chunk within 128B row

  // staging: round i covers rows i*32 + rq; source chunk XOR-swizzled by row&7
  const bf16_t* aptr[4];
  const bf16_t* bptr[4];
#pragma unroll
  for (int i = 0; i < 4; ++i) {
    int r = i * 32 + rq;
    int rr = (r < rows) ? r : 0;  // clamp gather for tail rows
    int t = tok[e * T_TOK + mt * BM + rr];
    int sc = ((c8 ^ (r & 7)) << 3);  // swizzled elem offset within row window
    aptr[i] = xb + (size_t)t * D_EMB + sc;
    bptr[i] = w1T + ((size_t)e * DFF + nt * BN + r) * D_EMB + sc;
  }
  int ldso = wv * 512;  // + i*2048 per round (elems); +lane*8 by HW

  int m0 = (wv & 1) * 64;
  int n0 = (wv >> 1) * 64;
  int lm = lane & 15;
  int lq = lane >> 4;
  int sw = lm & 7;  // read-side row swizzle key (rows are +multiples of 8)

  floatx4 acc[4][4];
#pragma unroll
  for (int i = 0; i < 4; ++i)
#pragma unroll
    for (int j = 0; j < 4; ++j)
#pragma unroll
      for (int r = 0; r < 4; ++r) acc[i][j][r] = 0.f;

  for (int kk = 0; kk < D_EMB; kk += BK) {
#pragma unroll
    for (int i = 0; i < 4; ++i) gl_lds16(aptr[i] + kk, As + i * 2048 + ldso);
#pragma unroll
    for (int i = 0; i < 4; ++i) gl_lds16(bptr[i] + kk, Bs + i * 2048 + ldso);
    __syncthreads();  // vmcnt(0) drain: tile ready
#pragma unroll
    for (int ks = 0; ks < BK; ks += 32) {
      int cb = (ks >> 3) + lq;          // chunk 0..7
      int co = ((cb ^ sw) << 3);        // swizzled elem offset in row
      bf16x8 af[4], bfr[4];
#pragma unroll
      for (int i = 0; i < 4; ++i)
        af[i] = *(const bf16x8*)&As[(m0 + i * 16 + lm) * BK + co];
#pragma unroll
      for (int j = 0; j < 4; ++j)
        bfr[j] = *(const bf16x8*)&Bs[(n0 + j * 16 + lm) * BK + co];
#pragma unroll
      for (int i = 0; i < 4; ++i)
#pragma unroll
        for (int j = 0; j < 4; ++j)
          acc[i][j] = __builtin_amdgcn_mfma_f32_16x16x32_bf16(af[i], bfr[j], acc[i][j], 0, 0, 0);
    }
    __syncthreads();  // all reads done before next stage
  }

  int hbase = offs[e] + mt * BM;
#pragma unroll
  for (int i = 0; i < 4; ++i) {
    int lr0 = m0 + i * 16 + lq * 4;
#pragma unroll
    for (int r = 0; r < 4; ++r) {
      int lr = lr0 + r;
      if (lr < rows) {
        size_t hrow = (size_t)(hbase + lr) * DFF;
#pragma unroll
        for (int j = 0; j < 4; ++j) {
          int col = nt * BN + n0 + j * 16 + lm;
          float v = acc[i][j][r] + b1p[e * DFF + col];
          h[hrow + col] = f2bf(fmaxf(v, 0.f));
        }
      }
    }
  }
}

// ---------------- GEMM2: out[tok] += gate * (h @ w2 + b2), K-split x2 ----------------
__global__ __launch_bounds__(256) void gemm2_k(
    const bf16_t* __restrict__ h, const bf16_t* __restrict__ w2T,
    const float* __restrict__ b2p, const int* __restrict__ cnt,
    const int* __restrict__ offs, const int* __restrict__ tok,
    const float* __restrict__ gate, float* __restrict__ out) {
  const int NT = D_EMB / BN;  // 8
  const int MT = T_TOK / BM;  // 64
  const int KS = 2;
  const int NWG = N_EXP * KS * MT * NT;  // 8192, %8==0 -> bijective swizzle
  int b0 = blockIdx.x;
  int bid = (b0 & 7) * (NWG >> 3) + (b0 >> 3);  // chunked per-XCD
  int e = bid / (KS * MT * NT);
  int rem2 = bid % (KS * MT * NT);
  int ksp = rem2 / (MT * NT);
  int rem = rem2 % (MT * NT);
  int mt = rem / NT;
  int nt = rem % NT;
  int cnte = cnt[e];
  if (mt * BM >= cnte) return;
  int rows = min(BM, cnte - mt * BM);

  __shared__ bf16_t As[BM * BK];
  __shared__ bf16_t Bs[BN * BK];
  __shared__ int stok[BM];
  __shared__ float sgate[BM];

  int tid = threadIdx.x;
  if (tid < BM) {
    int idx = e * T_TOK + mt * BM + ((tid < rows) ? tid : 0);
    stok[tid] = tok[idx];
    sgate[tid] = gate[idx];
  }
  // ordered before epilogue reads by the in-loop barriers (K-loop >= 1 iter)

  int lane = tid & 63;
  int wv = tid >> 6;
  int rq = tid >> 3;
  int c8 = tid & 7;

  // h rows are compacted: A-tile rows are CONTIGUOUS (no gather here)
  const bf16_t* aptr[4];
  const bf16_t* bptr[4];
#pragma unroll
  for (int i = 0; i < 4; ++i) {
    int r = i * 32 + rq;
    int rr = (r < rows) ? r : 0;  // don't read past expert's h region
    int sc = ((c8 ^ (r & 7)) << 3);
    aptr[i] = h + (size_t)(offs[e] + mt * BM + rr) * DFF + sc;
    bptr[i] = w2T + ((size_t)e * D_EMB + nt * BN + r) * DFF + sc;
  }
  int ldso = wv * 512;

  int m0 = (wv & 1) * 64;
  int n0 = (wv >> 1) * 64;
  int lm = lane & 15;
  int lq = lane >> 4;
  int sw = lm & 7;

  floatx4 acc[4][4];
#pragma unroll
  for (int i = 0; i < 4; ++i)
#pragma unroll
    for (int j = 0; j < 4; ++j)
#pragma unroll
      for (int r = 0; r < 4; ++r) acc[i][j][r] = 0.f;

  int kbeg = ksp * (DFF / KS);
  int kend = kbeg + DFF / KS;
  for (int kk = kbeg; kk < kend; kk += BK) {
#pragma unroll
    for (int i = 0; i < 4; ++i) gl_lds16(aptr[i] + kk, As + i * 2048 + ldso);
#pragma unroll
    for (int i = 0; i < 4; ++i) gl_lds16(bptr[i] + kk, Bs + i * 2048 + ldso);
    __syncthreads();
#pragma unroll
    for (int ks = 0; ks < BK; ks += 32) {
      int cb = (ks >> 3) + lq;
      int co = ((cb ^ sw) << 3);
      bf16x8 af[4], bfr[4];
#pragma unroll
      for (int i = 0; i < 4; ++i)
        af[i] = *(const bf16x8*)&As[(m0 + i * 16 + lm) * BK + co];
#pragma unroll
      for (int j = 0; j < 4; ++j)
        bfr[j] = *(const bf16x8*)&Bs[(n0 + j * 16 + lm) * BK + co];
#pragma unroll
      for (int i = 0; i < 4; ++i)
#pragma unroll
        for (int j = 0; j < 4; ++j)
          acc[i][j] = __builtin_amdgcn_mfma_f32_16x16x32_bf16(af[i], bfr[j], acc[i][j], 0, 0, 0);
    }
    __syncthreads();
  }

#pragma unroll
  for (int i = 0; i < 4; ++i) {
    int lr0 = m0 + i * 16 + lq * 4;
#pragma unroll
    for (int r = 0; r < 4; ++r) {
      int lr = lr0 + r;
      if (lr < rows) {
        int t = stok[lr];
        float g = sgate[lr];
#pragma unroll
        for (int j = 0; j < 4; ++j) {
          int col = nt * BN + n0 + j * 16 + lm;
          float bb = (ksp == 0) ? b2p[e * D_EMB + col] : 0.f;
          float v = g * (acc[i][j][r] + bb);
          unsafeAtomicAdd(&out[(size_t)t * D_EMB + col], v);
        }
      }
    }
  }
}

extern "C" void kernel_launch(void* const* d_in, const int* in_sizes, int n_in,
                              void* d_out, int out_size, void* d_ws, size_t ws_size,
                              hipStream_t stream) {
  const float* x  = (const float*)d_in[0];
  const float* nu = (const float*)d_in[1];
  const float* wg = (const float*)d_in[2];
  const float* bg = (const float*)d_in[3];
  const float* wn = (const float*)d_in[4];
  const float* bn = (const float*)d_in[5];
  const float* w1 = (const float*)d_in[6];
  const float* b1 = (const float*)d_in[7];
  const float* w2 = (const float*)d_in[8];
  const float* b2 = (const float*)d_in[9];
  float* out = (float*)d_out;

  char* ws = (char*)d_ws;
  size_t o = 0;
  int* cnt  = (int*)(ws + o);          // 8 ints
  int* offs = cnt + 8;                 // 9 ints (within 256B header)
  o += 256;
  int*   tok  = (int*)(ws + o);   o += (size_t)N_EXP * T_TOK * 4;
  float* gate = (float*)(ws + o); o += (size_t)N_EXP * T_TOK * 4;
  bf16_t* xb  = (bf16_t*)(ws + o); o += (size_t)T_TOK * D_EMB * 2;
  bf16_t* w1T = (bf16_t*)(ws + o); o += (size_t)N_EXP * D_EMB * DFF * 2;
  bf16_t* w2T = (bf16_t*)(ws + o); o += (size_t)N_EXP * D_EMB * DFF * 2;
  bf16_t* h   = (bf16_t*)(ws + o); o += (size_t)2 * T_TOK * DFF * 2;
  (void)o; (void)ws_size; (void)in_sizes; (void)n_in;

  hipMemsetAsync(cnt, 0, 256, stream);
  hipMemsetAsync(out, 0, (size_t)out_size * sizeof(float), stream);

  cvt_x_k<<<(T_TOK * D_EMB) / 1024, 256, 0, stream>>>(x, xb);
  tcvt_k<<<dim3(DFF / 32, D_EMB / 32, N_EXP), dim3(32, 8), 0, stream>>>(w1, w1T, D_EMB, DFF);
  tcvt_k<<<dim3(D_EMB / 32, DFF / 32, N_EXP), dim3(32, 8), 0, stream>>>(w2, w2T, DFF, D_EMB);
  router_k<<<T_TOK, 256, 0, stream>>>(x, nu, wg, bg, wn, bn, cnt, tok, gate);
  scan_k<<<1, 64, 0, stream>>>(cnt, offs);
  gemm1_k<<<N_EXP * (T_TOK / BM) * (DFF / BN), 256, 0, stream>>>(xb, w1T, b1, cnt, offs, tok, h);
  gemm2_k<<<N_EXP * 2 * (T_TOK / BM) * (D_EMB / BN), 256, 0, stream>>>(h, w2T, b2, cnt, offs, tok, gate, out);
}

// Round 5
// 865.059 us; speedup vs baseline: 1.2065x; 1.2065x over previous
//
#include <hip/hip_runtime.h>

// SparseMoE: B=4,S=2048 -> T=8192 tokens, D=1024, FF=4096, E=8, top-2.
// R5: router de-atomicized. Old router: 16384 single-lane device-scope
// atomicAdds to ONE cache line (cnt[0..7]) -> serialized L2 funnel, est.
// 150-350us (the constant ~750us "rest" bucket across R0-R4). New: router
// writes per-token (e1,e2,g1,g2); compact_k builds expert lists via LDS
// histogram (256 global atomics total, 64x fewer).
// gemm1 = R3 config (BK=32, best total); gemm2 = R4 config (BK=64,
// src-XOR-swizzle -> 0 bank conflicts, K-split x2).

#define T_TOK 8192
#define D_EMB 1024
#define DFF   4096
#define N_EXP 8
#define BM 128
#define BN 128

typedef __attribute__((ext_vector_type(8))) short bf16x8;
typedef __attribute__((ext_vector_type(4))) float floatx4;
typedef unsigned short bf16_t;

__device__ __forceinline__ bf16_t f2bf(float f) {
  union { float f; unsigned u; } a; a.f = f;
  unsigned u = a.u;
  return (bf16_t)((u + 0x7fffu + ((u >> 16) & 1u)) >> 16);  // RNE
}

// async global->LDS, 16B per lane. LDS dest = wave-uniform base + lane*16;
// global src is per-lane (gather + swizzle OK).
__device__ __forceinline__ void gl_lds16(const bf16_t* g, bf16_t* l) {
  __builtin_amdgcn_global_load_lds(
      (const __attribute__((address_space(1))) void*)g,
      (__attribute__((address_space(3))) void*)l, 16, 0, 0);
}

// ---------------- cvt x -> bf16 ----------------
__global__ __launch_bounds__(256) void cvt_x_k(const float* __restrict__ x,
                                               bf16_t* __restrict__ xb) {
  int i = (blockIdx.x * 256 + threadIdx.x) * 4;
  float4 v = *(const float4*)(x + i);
  ushort4 o;
  o.x = f2bf(v.x); o.y = f2bf(v.y); o.z = f2bf(v.z); o.w = f2bf(v.w);
  *(ushort4*)(xb + i) = o;
}

// ------------- transpose+cvt: in [E][K][N] f32 -> out [E][N][K] bf16 -------------
__global__ __launch_bounds__(256) void tcvt_k(const float* __restrict__ in,
                                              bf16_t* __restrict__ outp,
                                              int K, int N) {
  __shared__ float tile[32][33];
  int e  = blockIdx.z;
  int n0 = blockIdx.x * 32;
  int k0 = blockIdx.y * 32;
  int tx = threadIdx.x;  // 0..31
  int ty = threadIdx.y;  // 0..7
  const float* src = in + (size_t)e * K * N;
#pragma unroll
  for (int l = 0; l < 32; l += 8)
    tile[ty + l][tx] = src[(size_t)(k0 + ty + l) * N + (n0 + tx)];
  __syncthreads();
  bf16_t* dst = outp + (size_t)e * K * N;
#pragma unroll
  for (int l = 0; l < 32; l += 8)
    dst[(size_t)(n0 + ty + l) * K + (k0 + tx)] = f2bf(tile[tx][ty + l]);
}

// ---------------- router: per-token top-2, NO contended atomics ----------------
__global__ __launch_bounds__(256) void router_k(
    const float* __restrict__ x, const float* __restrict__ nu,
    const float* __restrict__ wg, const float* __restrict__ bgp,
    const float* __restrict__ wn, const float* __restrict__ bnp,
    int* __restrict__ sel, float2* __restrict__ gts) {
  int t = blockIdx.x;
  int tid = threadIdx.x;
  float gl[8] = {0,0,0,0,0,0,0,0};
  float nl[8] = {0,0,0,0,0,0,0,0};
  const float* xr = x + (size_t)t * D_EMB;
  for (int i = tid; i < D_EMB; i += 256) {
    float xv = xr[i];
    float4 a0 = *(const float4*)(wg + i * 8);
    float4 a1 = *(const float4*)(wg + i * 8 + 4);
    float4 c0 = *(const float4*)(wn + i * 8);
    float4 c1 = *(const float4*)(wn + i * 8 + 4);
    gl[0] += xv * a0.x; gl[1] += xv * a0.y; gl[2] += xv * a0.z; gl[3] += xv * a0.w;
    gl[4] += xv * a1.x; gl[5] += xv * a1.y; gl[6] += xv * a1.z; gl[7] += xv * a1.w;
    nl[0] += xv * c0.x; nl[1] += xv * c0.y; nl[2] += xv * c0.z; nl[3] += xv * c0.w;
    nl[4] += xv * c1.x; nl[5] += xv * c1.y; nl[6] += xv * c1.z; nl[7] += xv * c1.w;
  }
  __shared__ float red[4][16];
  int lane = tid & 63;
  int wv = tid >> 6;
#pragma unroll
  for (int o = 0; o < 16; ++o) {
    float v = (o < 8) ? gl[o] : nl[o - 8];
#pragma unroll
    for (int s = 32; s > 0; s >>= 1) v += __shfl_down(v, s, 64);
    if (lane == 0) red[wv][o] = v;
  }
  __syncthreads();
  if (tid == 0) {
    float noisy[8];
#pragma unroll
    for (int e = 0; e < 8; ++e) {
      float lg = red[0][e] + red[1][e] + red[2][e] + red[3][e] + bgp[e];
      float nz = red[0][8 + e] + red[1][8 + e] + red[2][8 + e] + red[3][8 + e] + bnp[e];
      float sp = fmaxf(nz, 0.f) + log1pf(expf(-fabsf(nz)));  // stable softplus
      noisy[e] = lg + nu[(size_t)t * 8 + e] * sp;
    }
    int e1 = 0;
#pragma unroll
    for (int e = 1; e < 8; ++e) if (noisy[e] > noisy[e1]) e1 = e;
    int e2 = -1;
#pragma unroll
    for (int e = 0; e < 8; ++e) {
      if (e == e1) continue;
      if (e2 < 0 || noisy[e] > noisy[e2]) e2 = e;
    }
    float d = expf(noisy[e2] - noisy[e1]);   // <= 1, no overflow
    float g1 = 1.f / (1.f + d);
    float g2 = d / (1.f + d);
    sel[t] = e1 | (e2 << 4);
    gts[t] = make_float2(g1, g2);
  }
}

// ---------------- compact: LDS-histogram expert-list build ----------------
__global__ __launch_bounds__(256) void compact_k(
    const int* __restrict__ sel, const float2* __restrict__ gts,
    int* __restrict__ cnt, int* __restrict__ tok, float* __restrict__ gate) {
  __shared__ int lcnt[N_EXP];
  __shared__ int lbase[N_EXP];
  int tid = threadIdx.x;
  int t = blockIdx.x * 256 + tid;
  if (tid < N_EXP) lcnt[tid] = 0;
  __syncthreads();
  int pk = sel[t];
  float2 g = gts[t];
  int e1 = pk & 15;
  int e2 = pk >> 4;
  int p1 = atomicAdd(&lcnt[e1], 1);  // LDS atomic: fast
  int p2 = atomicAdd(&lcnt[e2], 1);
  __syncthreads();
  if (tid < N_EXP) lbase[tid] = atomicAdd(&cnt[tid], lcnt[tid]);  // 8/block global
  __syncthreads();
  int q1 = lbase[e1] + p1;
  int q2 = lbase[e2] + p2;
  tok[e1 * T_TOK + q1] = t;  gate[e1 * T_TOK + q1] = g.x;
  tok[e2 * T_TOK + q2] = t;  gate[e2 * T_TOK + q2] = g.y;
}

// ---------------- scan (8 experts) ----------------
__global__ void scan_k(const int* __restrict__ cnt, int* __restrict__ offs) {
  if (threadIdx.x == 0 && blockIdx.x == 0) {
    int a = 0;
    for (int e = 0; e < N_EXP; ++e) { offs[e] = a; a += cnt[e]; }
    offs[N_EXP] = a;
  }
}

// ---------------- GEMM1: h = relu(x_gathered @ w1 + b1), bf16 out ----------------
// R3 config: 128x128, BK=32, 4 waves, single-buffer LDS, 2 barriers/K-step.
__global__ __launch_bounds__(256) void gemm1_k(
    const bf16_t* __restrict__ xb, const bf16_t* __restrict__ w1T,
    const float* __restrict__ b1p, const int* __restrict__ cnt,
    const int* __restrict__ offs, const int* __restrict__ tok,
    bf16_t* __restrict__ h) {
  const int BK1 = 32;
  const int NT = DFF / BN;    // 32
  const int MT = T_TOK / BM;  // 64
  const int NWG = N_EXP * MT * NT;  // 16384, %8==0 -> bijective swizzle
  int b0 = blockIdx.x;
  int bid = (b0 & 7) * (NWG >> 3) + (b0 >> 3);  // chunked per-XCD
  int e = bid / (MT * NT);
  int rem = bid % (MT * NT);
  int mt = rem / NT;
  int nt = rem % NT;
  int cnte = cnt[e];
  if (mt * BM >= cnte) return;
  int rows = min(BM, cnte - mt * BM);

  __shared__ bf16_t As[BM * BK1];  // 8 KB, linear (gl_lds dest)
  __shared__ bf16_t Bs[BN * BK1];  // 8 KB

  int tid = threadIdx.x;
  int lane = tid & 63;
  int wv = tid >> 6;          // 0..3
  int rq = tid >> 2;          // 0..63 (row within 64-row staging round)
  int c4 = tid & 3;           // 16B chunk within 64B row

  const bf16_t* aptr[2];
  const bf16_t* bptr[2];
#pragma unroll
  for (int i = 0; i < 2; ++i) {
    int r = i * 64 + rq;
    int rr = (r < rows) ? r : 0;  // clamp gather for tail rows
    int t = tok[e * T_TOK + mt * BM + rr];
    aptr[i] = xb + (size_t)t * D_EMB + c4 * 8;
    bptr[i] = w1T + ((size_t)e * DFF + nt * BN + r) * D_EMB + c4 * 8;
  }
  int ldso = wv * 512;

  int m0 = (wv & 1) * 64;
  int n0 = (wv >> 1) * 64;
  int lm = lane & 15;
  int lq = lane >> 4;

  floatx4 acc[4][4];
#pragma unroll
  for (int i = 0; i < 4; ++i)
#pragma unroll
    for (int j = 0; j < 4; ++j)
#pragma unroll
      for (int r = 0; r < 4; ++r) acc[i][j][r] = 0.f;

  for (int kk = 0; kk < D_EMB; kk += BK1) {
    gl_lds16(aptr[0] + kk, As + ldso);
    gl_lds16(aptr[1] + kk, As + 2048 + ldso);
    gl_lds16(bptr[0] + kk, Bs + ldso);
    gl_lds16(bptr[1] + kk, Bs + 2048 + ldso);
    __syncthreads();  // vmcnt(0) drain: tile ready
    bf16x8 af[4], bfr[4];
#pragma unroll
    for (int i = 0; i < 4; ++i)
      af[i] = *(const bf16x8*)&As[(m0 + i * 16 + lm) * BK1 + lq * 8];
#pragma unroll
    for (int j = 0; j < 4; ++j)
      bfr[j] = *(const bf16x8*)&Bs[(n0 + j * 16 + lm) * BK1 + lq * 8];
#pragma unroll
    for (int i = 0; i < 4; ++i)
#pragma unroll
      for (int j = 0; j < 4; ++j)
        acc[i][j] = __builtin_amdgcn_mfma_f32_16x16x32_bf16(af[i], bfr[j], acc[i][j], 0, 0, 0);
    __syncthreads();  // all reads done before next stage
  }

  int hbase = offs[e] + mt * BM;
#pragma unroll
  for (int i = 0; i < 4; ++i) {
    int lr0 = m0 + i * 16 + lq * 4;
#pragma unroll
    for (int r = 0; r < 4; ++r) {
      int lr = lr0 + r;
      if (lr < rows) {
        size_t hrow = (size_t)(hbase + lr) * DFF;
#pragma unroll
        for (int j = 0; j < 4; ++j) {
          int col = nt * BN + n0 + j * 16 + lm;
          float v = acc[i][j][r] + b1p[e * DFF + col];
          h[hrow + col] = f2bf(fmaxf(v, 0.f));
        }
      }
    }
  }
}

// ---------------- GEMM2: out[tok] += gate * (h @ w2 + b2), K-split x2 ----------------
// R4 config: BK=64, src-XOR-swizzled staging (0 bank conflicts).
__global__ __launch_bounds__(256) void gemm2_k(
    const bf16_t* __restrict__ h, const bf16_t* __restrict__ w2T,
    const float* __restrict__ b2p, const int* __restrict__ cnt,
    const int* __restrict__ offs, const int* __restrict__ tok,
    const float* __restrict__ gate, float* __restrict__ out) {
  const int BK2 = 64;
  const int NT = D_EMB / BN;  // 8
  const int MT = T_TOK / BM;  // 64
  const int KS = 2;
  const int NWG = N_EXP * KS * MT * NT;  // 8192, %8==0 -> bijective swizzle
  int b0 = blockIdx.x;
  int bid = (b0 & 7) * (NWG >> 3) + (b0 >> 3);  // chunked per-XCD
  int e = bid / (KS * MT * NT);
  int rem2 = bid % (KS * MT * NT);
  int ksp = rem2 / (MT * NT);
  int rem = rem2 % (MT * NT);
  int mt = rem / NT;
  int nt = rem % NT;
  int cnte = cnt[e];
  if (mt * BM >= cnte) return;
  int rows = min(BM, cnte - mt * BM);

  __shared__ bf16_t As[BM * BK2];
  __shared__ bf16_t Bs[BN * BK2];
  __shared__ int stok[BM];
  __shared__ float sgate[BM];

  int tid = threadIdx.x;
  if (tid < BM) {
    int idx = e * T_TOK + mt * BM + ((tid < rows) ? tid : 0);
    stok[tid] = tok[idx];
    sgate[tid] = gate[idx];
  }
  // ordered before epilogue reads by the in-loop barriers (K-loop >= 1 iter)

  int lane = tid & 63;
  int wv = tid >> 6;
  int rq = tid >> 3;
  int c8 = tid & 7;

  // h rows are compacted: A-tile rows are CONTIGUOUS (no gather here)
  const bf16_t* aptr[4];
  const bf16_t* bptr[4];
#pragma unroll
  for (int i = 0; i < 4; ++i) {
    int r = i * 32 + rq;
    int rr = (r < rows) ? r : 0;  // don't read past expert's h region
    int sc = ((c8 ^ (r & 7)) << 3);
    aptr[i] = h + (size_t)(offs[e] + mt * BM + rr) * DFF + sc;
    bptr[i] = w2T + ((size_t)e * D_EMB + nt * BN + r) * DFF + sc;
  }
  int ldso = wv * 512;

  int m0 = (wv & 1) * 64;
  int n0 = (wv >> 1) * 64;
  int lm = lane & 15;
  int lq = lane >> 4;
  int sw = lm & 7;

  floatx4 acc[4][4];
#pragma unroll
  for (int i = 0; i < 4; ++i)
#pragma unroll
    for (int j = 0; j < 4; ++j)
#pragma unroll
      for (int r = 0; r < 4; ++r) acc[i][j][r] = 0.f;

  int kbeg = ksp * (DFF / KS);
  int kend = kbeg + DFF / KS;
  for (int kk = kbeg; kk < kend; kk += BK2) {
#pragma unroll
    for (int i = 0; i < 4; ++i) gl_lds16(aptr[i] + kk, As + i * 2048 + ldso);
#pragma unroll
    for (int i = 0; i < 4; ++i) gl_lds16(bptr[i] + kk, Bs + i * 2048 + ldso);
    __syncthreads();
#pragma unroll
    for (int ks = 0; ks < BK2; ks += 32) {
      int cb = (ks >> 3) + lq;
      int co = ((cb ^ sw) << 3);
      bf16x8 af[4], bfr[4];
#pragma unroll
      for (int i = 0; i < 4; ++i)
        af[i] = *(const bf16x8*)&As[(m0 + i * 16 + lm) * BK2 + co];
#pragma unroll
      for (int j = 0; j < 4; ++j)
        bfr[j] = *(const bf16x8*)&Bs[(n0 + j * 16 + lm) * BK2 + co];
#pragma unroll
      for (int i = 0; i < 4; ++i)
#pragma unroll
        for (int j = 0; j < 4; ++j)
          acc[i][j] = __builtin_amdgcn_mfma_f32_16x16x32_bf16(af[i], bfr[j], acc[i][j], 0, 0, 0);
    }
    __syncthreads();
  }

#pragma unroll
  for (int i = 0; i < 4; ++i) {
    int lr0 = m0 + i * 16 + lq * 4;
#pragma unroll
    for (int r = 0; r < 4; ++r) {
      int lr = lr0 + r;
      if (lr < rows) {
        int t = stok[lr];
        float g = sgate[lr];
#pragma unroll
        for (int j = 0; j < 4; ++j) {
          int col = nt * BN + n0 + j * 16 + lm;
          float bb = (ksp == 0) ? b2p[e * D_EMB + col] : 0.f;
          float v = g * (acc[i][j][r] + bb);
          unsafeAtomicAdd(&out[(size_t)t * D_EMB + col], v);
        }
      }
    }
  }
}

extern "C" void kernel_launch(void* const* d_in, const int* in_sizes, int n_in,
                              void* d_out, int out_size, void* d_ws, size_t ws_size,
                              hipStream_t stream) {
  const float* x  = (const float*)d_in[0];
  const float* nu = (const float*)d_in[1];
  const float* wg = (const float*)d_in[2];
  const float* bg = (const float*)d_in[3];
  const float* wn = (const float*)d_in[4];
  const float* bn = (const float*)d_in[5];
  const float* w1 = (const float*)d_in[6];
  const float* b1 = (const float*)d_in[7];
  const float* w2 = (const float*)d_in[8];
  const float* b2 = (const float*)d_in[9];
  float* out = (float*)d_out;

  char* ws = (char*)d_ws;
  size_t o = 0;
  int* cnt  = (int*)(ws + o);          // 8 ints
  int* offs = cnt + 8;                 // 9 ints (within 256B header)
  o += 256;
  int*    tok  = (int*)(ws + o);    o += (size_t)N_EXP * T_TOK * 4;
  float*  gate = (float*)(ws + o);  o += (size_t)N_EXP * T_TOK * 4;
  int*    sel  = (int*)(ws + o);    o += (size_t)T_TOK * 4;
  float2* gts  = (float2*)(ws + o); o += (size_t)T_TOK * 8;
  bf16_t* xb  = (bf16_t*)(ws + o); o += (size_t)T_TOK * D_EMB * 2;
  bf16_t* w1T = (bf16_t*)(ws + o); o += (size_t)N_EXP * D_EMB * DFF * 2;
  bf16_t* w2T = (bf16_t*)(ws + o); o += (size_t)N_EXP * D_EMB * DFF * 2;
  bf16_t* h   = (bf16_t*)(ws + o); o += (size_t)2 * T_TOK * DFF * 2;
  (void)o; (void)ws_size; (void)in_sizes; (void)n_in;

  hipMemsetAsync(cnt, 0, 256, stream);
  hipMemsetAsync(out, 0, (size_t)out_size * sizeof(float), stream);

  cvt_x_k<<<(T_TOK * D_EMB) / 1024, 256, 0, stream>>>(x, xb);
  tcvt_k<<<dim3(DFF / 32, D_EMB / 32, N_EXP), dim3(32, 8), 0, stream>>>(w1, w1T, D_EMB, DFF);
  tcvt_k<<<dim3(D_EMB / 32, DFF / 32, N_EXP), dim3(32, 8), 0, stream>>>(w2, w2T, DFF, D_EMB);
  router_k<<<T_TOK, 256, 0, stream>>>(x, nu, wg, bg, wn, bn, sel, gts);
  compact_k<<<T_TOK / 256, 256, 0, stream>>>(sel, gts, cnt, tok, gate);
  scan_k<<<1, 64, 0, stream>>>(cnt, offs);
  gemm1_k<<<N_EXP * (T_TOK / BM) * (DFF / BN), 256, 0, stream>>>(xb, w1T, b1, cnt, offs, tok, h);
  gemm2_k<<<N_EXP * 2 * (T_TOK / BM) * (D_EMB / BN), 256, 0, stream>>>(h, w2T, b2, cnt, offs, tok, gate, out);
}